// Round 10
// baseline (4730.295 us; speedup 1.0000x reference)
//
#include <hip/hip_runtime.h>
#include <cstdint>
#include <cstddef>

// ---------------- problem constants ----------------
#define BB 128
#define NMAP 32
#define NPRIM 144
#define NCAP 4608      // 32*144
#define NCLS 10
#define ODIM 16
#define IDIM 8

// ws layout (float offsets)
#define WS_X1H  0                       // x1 hi bf16 NHWC ushort; later reused for Wt fp32 (5.9M fl)
#define WS_X1L  6553600                 // x1 lo bf16
#define WS_BH   13107200                // weights hi bf16: [81][256 oc][256 ic] ushort
#define WS_BL   15761408
#define WS_P    18415616                // conv2 out NHWC: [128*144][256]
#define WS_U    23134208                // squash:   [128][4608][8]
#define WS_V    27852800                // routing v: [128][10][16]
#define WS_H1   27873280                // dec h1: [128][512]
#define WS_H2   27938816                // dec h2: [128][1024]
#define WS_CLS  28069888                // argmax class per b (int), 128

// out layout (floats): [128*10 onehot][128*784 reconst][128*10 v_length]
#define OUT_REC  1280
#define OUT_LEN  101632

typedef __attribute__((ext_vector_type(8))) short short8;
typedef __attribute__((ext_vector_type(4))) float f32x4;

// round-to-nearest-even fp32 -> bf16 bits
static __device__ __forceinline__ ushort f2bf(float f) {
    uint u = __float_as_uint(f);
    u = (u + 0x7FFFu + ((u >> 16) & 1u)) >> 16;
    return (ushort)u;
}
static __device__ __forceinline__ float bf2f(ushort h) {
    return __uint_as_float(((uint)h) << 16);
}

// ---------------- kernels ----------------

// conv1 + bias + relu, emitting NHWC bf16 hi/lo directly.
__global__ __launch_bounds__(256) void k_conv1(const float* __restrict__ img,
                                               const float* __restrict__ w,
                                               const float* __restrict__ bias,
                                               ushort* __restrict__ x1h,
                                               ushort* __restrict__ x1l) {
    __shared__ float simg[252];   // 9 rows x 28 cols
    int bi = blockIdx.x;
    int y = bi % 20;
    int b = bi / 20;
    int oc = threadIdx.x;
    if (threadIdx.x < 252)
        simg[threadIdx.x] = img[(size_t)b * 784 + y * 28 + threadIdx.x];
    __syncthreads();

    float acc[20];
    float bv = bias[oc];
#pragma unroll
    for (int x = 0; x < 20; ++x) acc[x] = bv;
    const float* wp = w + oc * 81;
#pragma unroll
    for (int kh = 0; kh < 9; ++kh) {
        float r[28];
#pragma unroll
        for (int j = 0; j < 28; ++j) r[j] = simg[kh * 28 + j];
#pragma unroll
        for (int kw = 0; kw < 9; ++kw) {
            float wv = wp[kh * 9 + kw];
#pragma unroll
            for (int x = 0; x < 20; ++x)
                acc[x] = fmaf(wv, r[x + kw], acc[x]);
        }
    }
    size_t base = ((size_t)b * 400 + y * 20) * 256 + oc;
#pragma unroll
    for (int x = 0; x < 20; ++x) {
        float v = fmaxf(acc[x], 0.f);
        ushort h = f2bf(v);
        ushort lo = f2bf(v - bf2f(h));
        x1h[base + (size_t)x * 256] = h;
        x1l[base + (size_t)x * 256] = lo;
    }
}

// conv2 weights: c2w [oc][ic][81] fp32 -> bh/bl [t=81][oc][ic] bf16 hi/lo
__global__ __launch_bounds__(256) void k_prep_w(const float* __restrict__ w2,
                                                ushort* __restrict__ bh,
                                                ushort* __restrict__ bl) {
    int id = blockIdx.x * 256 + threadIdx.x;   // 65536 = oc*256 + ic
    const float* src = w2 + (size_t)id * 81;
#pragma unroll 9
    for (int t = 0; t < 81; ++t) {
        float v = src[t];
        ushort h = f2bf(v);
        ushort lo = f2bf(v - bf2f(h));
        bh[(size_t)t * 65536 + id] = h;
        bl[(size_t)t * 65536 + id] = lo;
    }
}

// ---- conv2 with LDS-resident x1 slab (exploits 81x conv tap reuse) ----
static __device__ __forceinline__ f32x4 mfma16(short8 a, short8 b, f32x4 c) {
    return __builtin_amdgcn_mfma_f32_16x16x32_bf16(a, b, c, 0, 0, 0);
}

template<int NMF>
static __device__ __forceinline__ void tap_loop(
    f32x4 (&acc)[5][2], const ushort* A_lds, const int* celloff,
    const ushort* __restrict__ wbh, const ushort* __restrict__ wbl,
    int boff0, int boff1, int bicc) {
    short8 ah[2][5], al[2][5], bhr[2][2], blr[2][2];
#pragma unroll
    for (int i = 0; i < NMF; ++i) {
        ah[0][i] = *(const short8*)(A_lds + celloff[i]);
        al[0][i] = *(const short8*)(A_lds + 16000 + celloff[i]);
    }
    bhr[0][0] = *(const short8*)(wbh + bicc + boff0);
    bhr[0][1] = *(const short8*)(wbh + bicc + boff1);
    blr[0][0] = *(const short8*)(wbl + bicc + boff0);
    blr[0][1] = *(const short8*)(wbl + bicc + boff1);

#pragma unroll 2
    for (int t = 0; t < 81; ++t) {
        const int cur = t & 1, nxt = cur ^ 1;
        if (t < 80) {
            int tn = t + 1;
            int kh = tn / 9, kw = tn - kh * 9;
            int tapoff = (kh * 20 + kw) * 40;
            size_t bko = (size_t)tn * 65536 + bicc;
            bhr[nxt][0] = *(const short8*)(wbh + bko + boff0);
            bhr[nxt][1] = *(const short8*)(wbh + bko + boff1);
            blr[nxt][0] = *(const short8*)(wbl + bko + boff0);
            blr[nxt][1] = *(const short8*)(wbl + bko + boff1);
#pragma unroll
            for (int i = 0; i < NMF; ++i) {
                ah[nxt][i] = *(const short8*)(A_lds + tapoff + celloff[i]);
                al[nxt][i] = *(const short8*)(A_lds + 16000 + tapoff + celloff[i]);
            }
        }
#pragma unroll
        for (int i = 0; i < NMF; ++i)
#pragma unroll
            for (int j = 0; j < 2; ++j)
                acc[i][j] = mfma16(ah[cur][i], bhr[cur][j], acc[i][j]);
#pragma unroll
        for (int i = 0; i < NMF; ++i)
#pragma unroll
            for (int j = 0; j < 2; ++j)
                acc[i][j] = mfma16(ah[cur][i], blr[cur][j], acc[i][j]);
#pragma unroll
        for (int i = 0; i < NMF; ++i)
#pragma unroll
            for (int j = 0; j < 2; ++j)
                acc[i][j] = mfma16(al[cur][i], bhr[cur][j], acc[i][j]);
    }
}

template<int MF0, int NMF>
static __device__ __forceinline__ void conv2s_epi(
    const f32x4 (&acc)[5][2], const float* __restrict__ bias,
    float* __restrict__ p, int b, int oc0, int nq, int r, int kq) {
#pragma unroll
    for (int j = 0; j < 2; ++j) {
        int oc = oc0 + (nq * 2 + j) * 16 + r;
        float bv = bias[oc];
#pragma unroll
        for (int i = 0; i < NMF; ++i) {
            int row = b * 144 + (MF0 + i) * 16 + kq * 4;
#pragma unroll
            for (int reg = 0; reg < 4; ++reg)
                p[(size_t)(row + reg) * 256 + oc] = acc[i][j][reg] + bv;
        }
    }
}

__global__ __launch_bounds__(512, 2) void k_conv2s(
    const ushort* __restrict__ x1h, const ushort* __restrict__ x1l,
    const ushort* __restrict__ wbh, const ushort* __restrict__ wbl,
    const float* __restrict__ bias, float* __restrict__ p) {
    __shared__ ushort A_lds[32000];   // [comp 2][cell 400][pitch 40 ushort]

    const int tid = threadIdx.x;
    const int lane = tid & 63;
    const int wv = tid >> 6;          // 0..7
    const int mh = wv >> 2;
    const int nq = wv & 3;
    const int b  = blockIdx.x >> 1;
    const int nt = blockIdx.x & 1;
    const int oc0 = nt * 128;
    const int r = lane & 15, kq = lane >> 4;
    const int MF0r = mh ? 5 : 0;

    int celloff[5];
#pragma unroll
    for (int i = 0; i < 5; ++i) {
        int lm = (MF0r + i) * 16 + r;
        celloff[i] = ((lm / 12) * 20 + (lm % 12)) * 40 + kq * 8;
    }
    const int boff0 = (oc0 + (nq * 2 + 0) * 16 + r) * 256 + kq * 8;
    const int boff1 = (oc0 + (nq * 2 + 1) * 16 + r) * 256 + kq * 8;

    f32x4 acc[5][2];
#pragma unroll
    for (int i = 0; i < 5; ++i)
#pragma unroll
        for (int j = 0; j < 2; ++j)
            acc[i][j] = (f32x4){0.f, 0.f, 0.f, 0.f};

    for (int icc = 0; icc < 8; ++icc) {
        if (icc) __syncthreads();
#pragma unroll
        for (int rd = 0; rd < 7; ++rd) {
            int idx = rd * 512 + tid;
            if (idx < 3200) {
                int comp = (idx >= 1600) ? 1 : 0;
                int ci = idx - comp * 1600;
                int cell = ci >> 2, cc = ci & 3;
                const ushort* src = (comp ? x1l : x1h) +
                    ((size_t)b * 400 + cell) * 256 + icc * 32 + cc * 8;
                short8 val = *(const short8*)src;
                *(short8*)(A_lds + comp * 16000 + cell * 40 + cc * 8) = val;
            }
        }
        __syncthreads();
        int bicc = icc * 32;
        if (mh == 0) tap_loop<5>(acc, A_lds, celloff, wbh, wbl, boff0, boff1, bicc);
        else         tap_loop<4>(acc, A_lds, celloff, wbh, wbl, boff0, boff1, bicc);
    }

    if (mh == 0) conv2s_epi<0, 5>(acc, bias, p, b, oc0, nq, r, kq);
    else         conv2s_epi<5, 4>(acc, bias, p, b, oc0, nq, r, kq);
}

// squash primary caps: p[(b*144+pos)][oc=i*32+m] -> u[b, n=m*144+pos, i]
__global__ __launch_bounds__(256) void k_squash(const float* __restrict__ p,
                                                float* __restrict__ u) {
    int id = blockIdx.x * 256 + threadIdx.x;   // B*4608
    int n = id % NCAP;
    int b = id / NCAP;
    int m = n / NPRIM, pos = n - m * NPRIM;
    const float* pp = p + ((size_t)b * 144 + pos) * 256 + m;
    float pv[8];
    float s2 = 0.f;
#pragma unroll
    for (int i = 0; i < 8; ++i) {
        pv[i] = pp[i * 32];
        s2 = fmaf(pv[i], pv[i], s2);
    }
    float f = (s2 / (1.f + s2)) / sqrtf(s2 + 1e-8f);
    float4 a = make_float4(f * pv[0], f * pv[1], f * pv[2], f * pv[3]);
    float4 c = make_float4(f * pv[4], f * pv[5], f * pv[6], f * pv[7]);
    float4* up = (float4*)(u + (size_t)id * 8);
    up[0] = a;
    up[1] = c;
}

// transpose routing weights: Wd[n][c][o][i] -> Wt[c][o*8+i][n]  (n = m*144+p)
__global__ __launch_bounds__(256) void k_prep_wt(const float* __restrict__ Wd,
                                                 float* __restrict__ Wt) {
    __shared__ float S[64][129];
    int c = blockIdx.x % NCLS;
    int nt = blockIdx.x / NCLS;    // 0..71
    int n0 = nt * 64;
    int tid = threadIdx.x;
#pragma unroll
    for (int rep = 0; rep < 32; ++rep) {
        int idx = rep * 256 + tid;
        int nl = idx >> 7, oi = idx & 127;
        S[nl][oi] = Wd[(size_t)(n0 + nl) * 1280 + c * 128 + oi];
    }
    __syncthreads();
#pragma unroll
    for (int rep = 0; rep < 32; ++rep) {
        int idx = rep * 256 + tid;
        int oi = idx >> 6, nl = idx & 63;
        Wt[((size_t)c * 128 + oi) * NCAP + n0 + nl] = S[nl][oi];
    }
}

// routing with register-resident u_hat: block = (batch-pair, class), 256 threads.
// 18 n per thread; u_hat for 2 batches packed bf16 hi/lo per uint -> pk[18][16]
// = 288 VGPRs. 256-thread block = 4 waves over 4 SIMDs = 1 wave/EU structurally,
// so launch_bounds(256,1) yields the full 512-VGPR cap (512-thread blocks were
// hard-capped at 128 VGPRs -> 992 MB scratch spill in R8/R9).
__global__ __launch_bounds__(256, 1) void k_route4(const float* __restrict__ u,
                                                   const float* __restrict__ Wt,
                                                   float* __restrict__ v_out) {
    __shared__ float part[4][2][17];
    __shared__ float sums[2][17];
    __shared__ float vsh[2][16];
    int c = blockIdx.x % NCLS;
    int bg = blockIdx.x / NCLS;       // 0..63
    int b0 = bg * 2;
    int tid = threadIdx.x;
    int lane = tid & 63, wvi = tid >> 6;
    const float* WtC = Wt + (size_t)c * 128 * NCAP;

    uint pk[18][16];
    float bij[18][2];

    // phase 1: u_hat from coalesced Wt stream (W read ONCE)
#pragma unroll
    for (int j = 0; j < 18; ++j) {
        int n = j * 256 + tid;
        const float4* up0 = (const float4*)(u + ((size_t)b0 * NCAP + n) * 8);
        const float4* up1 = (const float4*)(u + ((size_t)(b0 + 1) * NCAP + n) * 8);
        float4 a0 = up0[0], a1 = up0[1];
        float4 c0 = up1[0], c1 = up1[1];
        float u0[8] = {a0.x, a0.y, a0.z, a0.w, a1.x, a1.y, a1.z, a1.w};
        float u1[8] = {c0.x, c0.y, c0.z, c0.w, c1.x, c1.y, c1.z, c1.w};
#pragma unroll
        for (int o = 0; o < 16; ++o) {
            float s0 = 0.f, s1 = 0.f;
#pragma unroll
            for (int i = 0; i < 8; ++i) {
                float w = WtC[(size_t)(o * 8 + i) * NCAP + n];
                s0 = fmaf(w, u0[i], s0);
                s1 = fmaf(w, u1[i], s1);
            }
            uint ph = __float_as_uint(s1);
            ph = (ph + 0x7FFFu + ((ph >> 16) & 1u)) & 0xFFFF0000u;
            uint pl = __float_as_uint(s0);
            pl = (pl + 0x7FFFu + ((pl >> 16) & 1u)) >> 16;
            pk[j][o] = ph | pl;
        }
        bij[j][0] = 0.f;
        bij[j][1] = 0.f;
    }

    for (int iter = 0; iter < 3; ++iter) {
        float sZ[2] = {0.f, 0.f};
        float sS[2][16];
#pragma unroll
        for (int o = 0; o < 16; ++o) { sS[0][o] = 0.f; sS[1][o] = 0.f; }

#pragma unroll
        for (int j = 0; j < 18; ++j) {
            float e0, e1;
            if (iter == 0) {
                e0 = e1 = 1.f;
            } else {
                float a0 = 0.f, a1 = 0.f;
#pragma unroll
                for (int o = 0; o < 16; ++o) {
                    float f0 = __uint_as_float(pk[j][o] << 16);
                    float f1 = __uint_as_float(pk[j][o] & 0xFFFF0000u);
                    a0 = fmaf(f0, vsh[0][o], a0);
                    a1 = fmaf(f1, vsh[1][o], a1);
                }
                bij[j][0] += a0;
                bij[j][1] += a1;
                e0 = __expf(bij[j][0]);
                e1 = __expf(bij[j][1]);
            }
            sZ[0] += e0;
            sZ[1] += e1;
#pragma unroll
            for (int o = 0; o < 16; ++o) {
                float f0 = __uint_as_float(pk[j][o] << 16);
                float f1 = __uint_as_float(pk[j][o] & 0xFFFF0000u);
                sS[0][o] = fmaf(e0, f0, sS[0][o]);
                sS[1][o] = fmaf(e1, f1, sS[1][o]);
            }
        }

#pragma unroll
        for (int bb = 0; bb < 2; ++bb) {
            float z = sZ[bb];
#pragma unroll
            for (int d = 32; d >= 1; d >>= 1) z += __shfl_xor(z, d, 64);
            if (lane == 0) part[wvi][bb][0] = z;
#pragma unroll
            for (int o = 0; o < 16; ++o) {
                float s = sS[bb][o];
#pragma unroll
                for (int d = 32; d >= 1; d >>= 1) s += __shfl_xor(s, d, 64);
                if (lane == 0) part[wvi][bb][1 + o] = s;
            }
        }
        __syncthreads();
        if (tid < 34) {
            int bb = tid / 17, k = tid % 17;
            float s = 0.f;
#pragma unroll
            for (int w4 = 0; w4 < 4; ++w4) s += part[w4][bb][k];
            sums[bb][k] = s;
        }
        __syncthreads();
        if (tid < 2) {
            float Z = sums[tid][0];
            float s[16];
            float s2 = 0.f;
#pragma unroll
            for (int o = 0; o < 16; ++o) {
                s[o] = sums[tid][1 + o] / Z;
                s2 = fmaf(s[o], s[o], s2);
            }
            float f = (s2 / (1.f + s2)) / sqrtf(s2 + 1e-8f);
#pragma unroll
            for (int o = 0; o < 16; ++o) vsh[tid][o] = f * s[o];
        }
        __syncthreads();
    }
    if (tid < 32) {
        int bb = tid >> 4, o = tid & 15;
        v_out[((size_t)(b0 + bb) * NCLS + c) * 16 + o] = vsh[bb][o];
    }
}

// head: v_length, argmax, one-hot
__global__ __launch_bounds__(64) void k_head(const float* __restrict__ v,
                                             float* __restrict__ out,
                                             int* __restrict__ cls_ws) {
    __shared__ float len2[NCLS];
    __shared__ int cls_sh;
    int b = blockIdx.x, tid = threadIdx.x;
    if (tid < NCLS) {
        float s2 = 0.f;
#pragma unroll
        for (int o = 0; o < 16; ++o) {
            float t = v[((size_t)b * NCLS + tid) * 16 + o];
            s2 = fmaf(t, t, s2);
        }
        len2[tid] = s2;
        out[OUT_LEN + b * NCLS + tid] = sqrtf(s2);
    }
    __syncthreads();
    if (tid == 0) {
        int best = 0;
        float bv = len2[0];
        for (int c2 = 1; c2 < NCLS; ++c2)
            if (len2[c2] > bv) { bv = len2[c2]; best = c2; }
        cls_sh = best;
        cls_ws[b] = best;
    }
    __syncthreads();
    if (tid < NCLS) out[b * NCLS + tid] = (tid == cls_sh) ? 1.0f : 0.0f;
}

// decoder layer 1
__global__ __launch_bounds__(256) void k_dec1(const float* __restrict__ v,
                                              const int* __restrict__ cls_ws,
                                              const float* __restrict__ w1,
                                              const float* __restrict__ b1,
                                              float* __restrict__ h1) {
    int id = blockIdx.x * 256 + threadIdx.x;  // B*512
    int j = id % 512, b = id / 512;
    int cls = cls_ws[b];
    const float* vp = v + ((size_t)b * NCLS + cls) * 16;
    float acc = b1[j];
#pragma unroll
    for (int o = 0; o < 16; ++o)
        acc = fmaf(vp[o], w1[(size_t)(cls * 16 + o) * 512 + j], acc);
    h1[id] = fmaxf(acc, 0.f);
}

// decoder layer 2
__global__ __launch_bounds__(256) void k_dec2(const float* __restrict__ h1,
                                              const float* __restrict__ w2,
                                              const float* __restrict__ b2,
                                              float* __restrict__ h2) {
    __shared__ float hs[512];
    int bi = blockIdx.x;
    int jc = bi % 4;
    int b = bi / 4;
    int tid = threadIdx.x;
    hs[tid] = h1[b * 512 + tid];
    hs[tid + 256] = h1[b * 512 + tid + 256];
    __syncthreads();
    int j = jc * 256 + tid;
    float acc = b2[j];
#pragma unroll 8
    for (int k = 0; k < 512; ++k)
        acc = fmaf(hs[k], w2[(size_t)k * 1024 + j], acc);
    h2[b * 1024 + j] = fmaxf(acc, 0.f);
}

// decoder layer 3 + sigmoid
__global__ __launch_bounds__(256) void k_dec3(const float* __restrict__ h2,
                                              const float* __restrict__ w3,
                                              const float* __restrict__ b3,
                                              float* __restrict__ out) {
    __shared__ float hs[1024];
    int bi = blockIdx.x;
    int jc = bi % 4;
    int b = bi / 4;
    int tid = threadIdx.x;
#pragma unroll
    for (int t = 0; t < 4; ++t) hs[tid + t * 256] = h2[b * 1024 + tid + t * 256];
    __syncthreads();
    int j = jc * 256 + tid;
    if (j < 784) {
        float acc = b3[j];
#pragma unroll 8
        for (int k = 0; k < 1024; ++k)
            acc = fmaf(hs[k], w3[(size_t)k * 784 + j], acc);
        out[OUT_REC + b * 784 + j] = 1.f / (1.f + __expf(-acc));
    }
}

// ---------------- launcher ----------------
extern "C" void kernel_launch(void* const* d_in, const int* in_sizes, int n_in,
                              void* d_out, int out_size, void* d_ws, size_t ws_size,
                              hipStream_t stream) {
    const float* imgs = (const float*)d_in[0];
    const float* c1w  = (const float*)d_in[1];
    const float* c1b  = (const float*)d_in[2];
    const float* c2w  = (const float*)d_in[3];
    const float* c2b  = (const float*)d_in[4];
    const float* Wd   = (const float*)d_in[5];
    const float* dw1  = (const float*)d_in[6];
    const float* db1  = (const float*)d_in[7];
    const float* dw2  = (const float*)d_in[8];
    const float* db2  = (const float*)d_in[9];
    const float* dw3  = (const float*)d_in[10];
    const float* db3  = (const float*)d_in[11];

    float* out = (float*)d_out;
    float* ws  = (float*)d_ws;
    ushort* x1h = (ushort*)(ws + WS_X1H);
    ushort* x1l = (ushort*)(ws + WS_X1L);
    ushort* wbh = (ushort*)(ws + WS_BH);
    ushort* wbl = (ushort*)(ws + WS_BL);
    float* p    = ws + WS_P;
    float* u    = ws + WS_U;
    float* v    = ws + WS_V;
    float* h1   = ws + WS_H1;
    float* h2   = ws + WS_H2;
    int*   cls  = (int*)(ws + WS_CLS);
    float* wt32 = ws + WS_X1H;   // reuses x1h region (dead after k_conv2s)

    k_conv1<<<BB * 20, 256, 0, stream>>>(imgs, c1w, c1b, x1h, x1l);
    k_prep_w<<<256, 256, 0, stream>>>(c2w, wbh, wbl);
    k_conv2s<<<BB * 2, 512, 0, stream>>>(x1h, x1l, wbh, wbl, c2b, p);
    k_squash<<<BB * NCAP / 256, 256, 0, stream>>>(p, u);
    k_prep_wt<<<720, 256, 0, stream>>>(Wd, wt32);   // after conv2s: x1h region now free
    k_route4<<<(BB / 2) * NCLS, 256, 0, stream>>>(u, wt32, v);
    k_head<<<BB, 64, 0, stream>>>(v, out, cls);
    k_dec1<<<BB * 512 / 256, 256, 0, stream>>>(v, cls, dw1, db1, h1);
    k_dec2<<<BB * 4, 256, 0, stream>>>(h1, dw2, db2, h2);
    k_dec3<<<BB * 4, 256, 0, stream>>>(h2, dw3, db3, out);
}

// Round 11
// 1301.019 us; speedup vs baseline: 3.6358x; 3.6358x over previous
//
#include <hip/hip_runtime.h>
#include <cstdint>
#include <cstddef>

// ---------------- problem constants ----------------
#define BB 128
#define NMAP 32
#define NPRIM 144
#define NCAP 4608      // 32*144
#define NCLS 10
#define ODIM 16
#define IDIM 8

// ws layout (float offsets)
#define WS_X1H  0                       // x1 hi bf16 NHWC ushort; later reused for Wt fp32 (5.9M fl)
#define WS_X1L  6553600                 // x1 lo bf16
#define WS_BH   13107200                // weights hi bf16: [81][256 oc][256 ic] ushort
#define WS_BL   15761408
#define WS_P    18415616                // conv2 out NHWC: [128*144][256]
#define WS_U    23134208                // squash:   [128][4608][8]
#define WS_V    27852800                // routing v: [128][10][16]
#define WS_H1   27873280                // dec h1: [128][512]
#define WS_H2   27938816                // dec h2: [128][1024]
#define WS_CLS  28069888                // argmax class per b (int), 128

// out layout (floats): [128*10 onehot][128*784 reconst][128*10 v_length]
#define OUT_REC  1280
#define OUT_LEN  101632

typedef __attribute__((ext_vector_type(8))) short short8;
typedef __attribute__((ext_vector_type(4))) float f32x4;

// round-to-nearest-even fp32 -> bf16 bits
static __device__ __forceinline__ ushort f2bf(float f) {
    uint u = __float_as_uint(f);
    u = (u + 0x7FFFu + ((u >> 16) & 1u)) >> 16;
    return (ushort)u;
}
static __device__ __forceinline__ float bf2f(ushort h) {
    return __uint_as_float(((uint)h) << 16);
}

// ---------------- kernels ----------------

// conv1 + bias + relu, emitting NHWC bf16 hi/lo directly.
__global__ __launch_bounds__(256) void k_conv1(const float* __restrict__ img,
                                               const float* __restrict__ w,
                                               const float* __restrict__ bias,
                                               ushort* __restrict__ x1h,
                                               ushort* __restrict__ x1l) {
    __shared__ float simg[252];   // 9 rows x 28 cols
    int bi = blockIdx.x;
    int y = bi % 20;
    int b = bi / 20;
    int oc = threadIdx.x;
    if (threadIdx.x < 252)
        simg[threadIdx.x] = img[(size_t)b * 784 + y * 28 + threadIdx.x];
    __syncthreads();

    float acc[20];
    float bv = bias[oc];
#pragma unroll
    for (int x = 0; x < 20; ++x) acc[x] = bv;
    const float* wp = w + oc * 81;
#pragma unroll
    for (int kh = 0; kh < 9; ++kh) {
        float r[28];
#pragma unroll
        for (int j = 0; j < 28; ++j) r[j] = simg[kh * 28 + j];
#pragma unroll
        for (int kw = 0; kw < 9; ++kw) {
            float wv = wp[kh * 9 + kw];
#pragma unroll
            for (int x = 0; x < 20; ++x)
                acc[x] = fmaf(wv, r[x + kw], acc[x]);
        }
    }
    size_t base = ((size_t)b * 400 + y * 20) * 256 + oc;
#pragma unroll
    for (int x = 0; x < 20; ++x) {
        float v = fmaxf(acc[x], 0.f);
        ushort h = f2bf(v);
        ushort lo = f2bf(v - bf2f(h));
        x1h[base + (size_t)x * 256] = h;
        x1l[base + (size_t)x * 256] = lo;
    }
}

// conv2 weights: c2w [oc][ic][81] fp32 -> bh/bl [t=81][oc][ic] bf16 hi/lo
__global__ __launch_bounds__(256) void k_prep_w(const float* __restrict__ w2,
                                                ushort* __restrict__ bh,
                                                ushort* __restrict__ bl) {
    int id = blockIdx.x * 256 + threadIdx.x;   // 65536 = oc*256 + ic
    const float* src = w2 + (size_t)id * 81;
#pragma unroll 9
    for (int t = 0; t < 81; ++t) {
        float v = src[t];
        ushort h = f2bf(v);
        ushort lo = f2bf(v - bf2f(h));
        bh[(size_t)t * 65536 + id] = h;
        bl[(size_t)t * 65536 + id] = lo;
    }
}

// ---- conv2 with LDS-resident x1 slab (exploits 81x conv tap reuse) ----
static __device__ __forceinline__ f32x4 mfma16(short8 a, short8 b, f32x4 c) {
    return __builtin_amdgcn_mfma_f32_16x16x32_bf16(a, b, c, 0, 0, 0);
}

template<int NMF>
static __device__ __forceinline__ void tap_loop(
    f32x4 (&acc)[5][2], const ushort* A_lds, const int* celloff,
    const ushort* __restrict__ wbh, const ushort* __restrict__ wbl,
    int boff0, int boff1, int bicc) {
    short8 ah[2][5], al[2][5], bhr[2][2], blr[2][2];
#pragma unroll
    for (int i = 0; i < NMF; ++i) {
        ah[0][i] = *(const short8*)(A_lds + celloff[i]);
        al[0][i] = *(const short8*)(A_lds + 16000 + celloff[i]);
    }
    bhr[0][0] = *(const short8*)(wbh + bicc + boff0);
    bhr[0][1] = *(const short8*)(wbh + bicc + boff1);
    blr[0][0] = *(const short8*)(wbl + bicc + boff0);
    blr[0][1] = *(const short8*)(wbl + bicc + boff1);

#pragma unroll 2
    for (int t = 0; t < 81; ++t) {
        const int cur = t & 1, nxt = cur ^ 1;
        if (t < 80) {
            int tn = t + 1;
            int kh = tn / 9, kw = tn - kh * 9;
            int tapoff = (kh * 20 + kw) * 40;
            size_t bko = (size_t)tn * 65536 + bicc;
            bhr[nxt][0] = *(const short8*)(wbh + bko + boff0);
            bhr[nxt][1] = *(const short8*)(wbh + bko + boff1);
            blr[nxt][0] = *(const short8*)(wbl + bko + boff0);
            blr[nxt][1] = *(const short8*)(wbl + bko + boff1);
#pragma unroll
            for (int i = 0; i < NMF; ++i) {
                ah[nxt][i] = *(const short8*)(A_lds + tapoff + celloff[i]);
                al[nxt][i] = *(const short8*)(A_lds + 16000 + tapoff + celloff[i]);
            }
        }
#pragma unroll
        for (int i = 0; i < NMF; ++i)
#pragma unroll
            for (int j = 0; j < 2; ++j)
                acc[i][j] = mfma16(ah[cur][i], bhr[cur][j], acc[i][j]);
#pragma unroll
        for (int i = 0; i < NMF; ++i)
#pragma unroll
            for (int j = 0; j < 2; ++j)
                acc[i][j] = mfma16(ah[cur][i], blr[cur][j], acc[i][j]);
#pragma unroll
        for (int i = 0; i < NMF; ++i)
#pragma unroll
            for (int j = 0; j < 2; ++j)
                acc[i][j] = mfma16(al[cur][i], bhr[cur][j], acc[i][j]);
    }
}

template<int MF0, int NMF>
static __device__ __forceinline__ void conv2s_epi(
    const f32x4 (&acc)[5][2], const float* __restrict__ bias,
    float* __restrict__ p, int b, int oc0, int nq, int r, int kq) {
#pragma unroll
    for (int j = 0; j < 2; ++j) {
        int oc = oc0 + (nq * 2 + j) * 16 + r;
        float bv = bias[oc];
#pragma unroll
        for (int i = 0; i < NMF; ++i) {
            int row = b * 144 + (MF0 + i) * 16 + kq * 4;
#pragma unroll
            for (int reg = 0; reg < 4; ++reg)
                p[(size_t)(row + reg) * 256 + oc] = acc[i][j][reg] + bv;
        }
    }
}

__global__ __launch_bounds__(512, 2) void k_conv2s(
    const ushort* __restrict__ x1h, const ushort* __restrict__ x1l,
    const ushort* __restrict__ wbh, const ushort* __restrict__ wbl,
    const float* __restrict__ bias, float* __restrict__ p) {
    __shared__ ushort A_lds[32000];   // [comp 2][cell 400][pitch 40 ushort]

    const int tid = threadIdx.x;
    const int lane = tid & 63;
    const int wv = tid >> 6;          // 0..7
    const int mh = wv >> 2;
    const int nq = wv & 3;
    const int b  = blockIdx.x >> 1;
    const int nt = blockIdx.x & 1;
    const int oc0 = nt * 128;
    const int r = lane & 15, kq = lane >> 4;
    const int MF0r = mh ? 5 : 0;

    int celloff[5];
#pragma unroll
    for (int i = 0; i < 5; ++i) {
        int lm = (MF0r + i) * 16 + r;
        celloff[i] = ((lm / 12) * 20 + (lm % 12)) * 40 + kq * 8;
    }
    const int boff0 = (oc0 + (nq * 2 + 0) * 16 + r) * 256 + kq * 8;
    const int boff1 = (oc0 + (nq * 2 + 1) * 16 + r) * 256 + kq * 8;

    f32x4 acc[5][2];
#pragma unroll
    for (int i = 0; i < 5; ++i)
#pragma unroll
        for (int j = 0; j < 2; ++j)
            acc[i][j] = (f32x4){0.f, 0.f, 0.f, 0.f};

    for (int icc = 0; icc < 8; ++icc) {
        if (icc) __syncthreads();
#pragma unroll
        for (int rd = 0; rd < 7; ++rd) {
            int idx = rd * 512 + tid;
            if (idx < 3200) {
                int comp = (idx >= 1600) ? 1 : 0;
                int ci = idx - comp * 1600;
                int cell = ci >> 2, cc = ci & 3;
                const ushort* src = (comp ? x1l : x1h) +
                    ((size_t)b * 400 + cell) * 256 + icc * 32 + cc * 8;
                short8 val = *(const short8*)src;
                *(short8*)(A_lds + comp * 16000 + cell * 40 + cc * 8) = val;
            }
        }
        __syncthreads();
        int bicc = icc * 32;
        if (mh == 0) tap_loop<5>(acc, A_lds, celloff, wbh, wbl, boff0, boff1, bicc);
        else         tap_loop<4>(acc, A_lds, celloff, wbh, wbl, boff0, boff1, bicc);
    }

    if (mh == 0) conv2s_epi<0, 5>(acc, bias, p, b, oc0, nq, r, kq);
    else         conv2s_epi<5, 4>(acc, bias, p, b, oc0, nq, r, kq);
}

// squash primary caps: p[(b*144+pos)][oc=i*32+m] -> u[b, n=m*144+pos, i]
__global__ __launch_bounds__(256) void k_squash(const float* __restrict__ p,
                                                float* __restrict__ u) {
    int id = blockIdx.x * 256 + threadIdx.x;   // B*4608
    int n = id % NCAP;
    int b = id / NCAP;
    int m = n / NPRIM, pos = n - m * NPRIM;
    const float* pp = p + ((size_t)b * 144 + pos) * 256 + m;
    float pv[8];
    float s2 = 0.f;
#pragma unroll
    for (int i = 0; i < 8; ++i) {
        pv[i] = pp[i * 32];
        s2 = fmaf(pv[i], pv[i], s2);
    }
    float f = (s2 / (1.f + s2)) / sqrtf(s2 + 1e-8f);
    float4 a = make_float4(f * pv[0], f * pv[1], f * pv[2], f * pv[3]);
    float4 c = make_float4(f * pv[4], f * pv[5], f * pv[6], f * pv[7]);
    float4* up = (float4*)(u + (size_t)id * 8);
    up[0] = a;
    up[1] = c;
}

// transpose routing weights: Wd[n][c][o][i] -> Wt[c][o*8+i][n]  (n = m*144+p)
__global__ __launch_bounds__(256) void k_prep_wt(const float* __restrict__ Wd,
                                                 float* __restrict__ Wt) {
    __shared__ float S[64][129];
    int c = blockIdx.x % NCLS;
    int nt = blockIdx.x / NCLS;    // 0..71
    int n0 = nt * 64;
    int tid = threadIdx.x;
#pragma unroll
    for (int rep = 0; rep < 32; ++rep) {
        int idx = rep * 256 + tid;
        int nl = idx >> 7, oi = idx & 127;
        S[nl][oi] = Wd[(size_t)(n0 + nl) * 1280 + c * 128 + oi];
    }
    __syncthreads();
#pragma unroll
    for (int rep = 0; rep < 32; ++rep) {
        int idx = rep * 256 + tid;
        int oi = idx >> 6, nl = idx & 63;
        Wt[((size_t)c * 128 + oi) * NCAP + n0 + nl] = S[nl][oi];
    }
}

// routing, R7-proven structure (2-batch, uh in regs transiently per j, single
// W pass per iter) but reading COALESCED Wt[c][o*8+i][n] dword streams.
// ~150 VGPRs (R10 proved >=288 register-resident state is architecturally
// impossible: 256 addressable VGPR max).
__global__ __launch_bounds__(256) void k_route5(const float* __restrict__ u,
                                                const float* __restrict__ Wt,
                                                float* __restrict__ v_out) {
    __shared__ float part[4][2][17];
    __shared__ float sums[2][17];
    __shared__ float vsh[2][16];
    int c = blockIdx.x % NCLS;
    int bg = blockIdx.x / NCLS;       // 0..63
    int b0 = bg * 2;
    int tid = threadIdx.x;
    int lane = tid & 63, wvi = tid >> 6;
    const float* WtC = Wt + (size_t)c * 128 * NCAP;

    float bij[18][2];
#pragma unroll
    for (int j = 0; j < 18; ++j) { bij[j][0] = 0.f; bij[j][1] = 0.f; }

    for (int iter = 0; iter < 3; ++iter) {
        float sZ[2] = {0.f, 0.f};
        float sS[2][16];
#pragma unroll
        for (int o = 0; o < 16; ++o) { sS[0][o] = 0.f; sS[1][o] = 0.f; }

        for (int j = 0; j < 18; ++j) {
            int n = j * 256 + tid;
            const float4* up0 = (const float4*)(u + ((size_t)b0 * NCAP + n) * 8);
            const float4* up1 = (const float4*)(u + ((size_t)(b0 + 1) * NCAP + n) * 8);
            float4 a0 = up0[0], a1 = up0[1];
            float4 c0 = up1[0], c1 = up1[1];
            float u0[8] = {a0.x, a0.y, a0.z, a0.w, a1.x, a1.y, a1.z, a1.w};
            float u1[8] = {c0.x, c0.y, c0.z, c0.w, c1.x, c1.y, c1.z, c1.w};
            float uh[2][16];
#pragma unroll
            for (int o = 0; o < 16; ++o) {
                float s0 = 0.f, s1 = 0.f;
#pragma unroll
                for (int i = 0; i < 8; ++i) {
                    float w = WtC[(size_t)(o * 8 + i) * NCAP + n];   // coalesced dword
                    s0 = fmaf(w, u0[i], s0);
                    s1 = fmaf(w, u1[i], s1);
                }
                uh[0][o] = s0;
                uh[1][o] = s1;
            }
#pragma unroll
            for (int bb = 0; bb < 2; ++bb) {
                float e;
                if (iter == 0) {
                    e = 1.f;
                } else {
                    float agr = 0.f;
#pragma unroll
                    for (int o = 0; o < 16; ++o) agr = fmaf(uh[bb][o], vsh[bb][o], agr);
                    bij[j][bb] += agr;
                    e = __expf(bij[j][bb]);
                }
                sZ[bb] += e;
#pragma unroll
                for (int o = 0; o < 16; ++o) sS[bb][o] = fmaf(e, uh[bb][o], sS[bb][o]);
            }
        }

#pragma unroll
        for (int bb = 0; bb < 2; ++bb) {
            float z = sZ[bb];
#pragma unroll
            for (int d = 32; d >= 1; d >>= 1) z += __shfl_xor(z, d, 64);
            if (lane == 0) part[wvi][bb][0] = z;
#pragma unroll
            for (int o = 0; o < 16; ++o) {
                float s = sS[bb][o];
#pragma unroll
                for (int d = 32; d >= 1; d >>= 1) s += __shfl_xor(s, d, 64);
                if (lane == 0) part[wvi][bb][1 + o] = s;
            }
        }
        __syncthreads();
        if (tid < 34) {
            int bb = tid / 17, k = tid % 17;
            float s = 0.f;
#pragma unroll
            for (int w4 = 0; w4 < 4; ++w4) s += part[w4][bb][k];
            sums[bb][k] = s;
        }
        __syncthreads();
        if (tid < 2) {
            float Z = sums[tid][0];
            float s[16];
            float s2 = 0.f;
#pragma unroll
            for (int o = 0; o < 16; ++o) {
                s[o] = sums[tid][1 + o] / Z;
                s2 = fmaf(s[o], s[o], s2);
            }
            float f = (s2 / (1.f + s2)) / sqrtf(s2 + 1e-8f);
#pragma unroll
            for (int o = 0; o < 16; ++o) vsh[tid][o] = f * s[o];
        }
        __syncthreads();
    }
    if (tid < 32) {
        int bb = tid >> 4, o = tid & 15;
        v_out[((size_t)(b0 + bb) * NCLS + c) * 16 + o] = vsh[bb][o];
    }
}

// head: v_length, argmax, one-hot
__global__ __launch_bounds__(64) void k_head(const float* __restrict__ v,
                                             float* __restrict__ out,
                                             int* __restrict__ cls_ws) {
    __shared__ float len2[NCLS];
    __shared__ int cls_sh;
    int b = blockIdx.x, tid = threadIdx.x;
    if (tid < NCLS) {
        float s2 = 0.f;
#pragma unroll
        for (int o = 0; o < 16; ++o) {
            float t = v[((size_t)b * NCLS + tid) * 16 + o];
            s2 = fmaf(t, t, s2);
        }
        len2[tid] = s2;
        out[OUT_LEN + b * NCLS + tid] = sqrtf(s2);
    }
    __syncthreads();
    if (tid == 0) {
        int best = 0;
        float bv = len2[0];
        for (int c2 = 1; c2 < NCLS; ++c2)
            if (len2[c2] > bv) { bv = len2[c2]; best = c2; }
        cls_sh = best;
        cls_ws[b] = best;
    }
    __syncthreads();
    if (tid < NCLS) out[b * NCLS + tid] = (tid == cls_sh) ? 1.0f : 0.0f;
}

// decoder layer 1
__global__ __launch_bounds__(256) void k_dec1(const float* __restrict__ v,
                                              const int* __restrict__ cls_ws,
                                              const float* __restrict__ w1,
                                              const float* __restrict__ b1,
                                              float* __restrict__ h1) {
    int id = blockIdx.x * 256 + threadIdx.x;  // B*512
    int j = id % 512, b = id / 512;
    int cls = cls_ws[b];
    const float* vp = v + ((size_t)b * NCLS + cls) * 16;
    float acc = b1[j];
#pragma unroll
    for (int o = 0; o < 16; ++o)
        acc = fmaf(vp[o], w1[(size_t)(cls * 16 + o) * 512 + j], acc);
    h1[id] = fmaxf(acc, 0.f);
}

// decoder layer 2
__global__ __launch_bounds__(256) void k_dec2(const float* __restrict__ h1,
                                              const float* __restrict__ w2,
                                              const float* __restrict__ b2,
                                              float* __restrict__ h2) {
    __shared__ float hs[512];
    int bi = blockIdx.x;
    int jc = bi % 4;
    int b = bi / 4;
    int tid = threadIdx.x;
    hs[tid] = h1[b * 512 + tid];
    hs[tid + 256] = h1[b * 512 + tid + 256];
    __syncthreads();
    int j = jc * 256 + tid;
    float acc = b2[j];
#pragma unroll 8
    for (int k = 0; k < 512; ++k)
        acc = fmaf(hs[k], w2[(size_t)k * 1024 + j], acc);
    h2[b * 1024 + j] = fmaxf(acc, 0.f);
}

// decoder layer 3 + sigmoid
__global__ __launch_bounds__(256) void k_dec3(const float* __restrict__ h2,
                                              const float* __restrict__ w3,
                                              const float* __restrict__ b3,
                                              float* __restrict__ out) {
    __shared__ float hs[1024];
    int bi = blockIdx.x;
    int jc = bi % 4;
    int b = bi / 4;
    int tid = threadIdx.x;
#pragma unroll
    for (int t = 0; t < 4; ++t) hs[tid + t * 256] = h2[b * 1024 + tid + t * 256];
    __syncthreads();
    int j = jc * 256 + tid;
    if (j < 784) {
        float acc = b3[j];
#pragma unroll 8
        for (int k = 0; k < 1024; ++k)
            acc = fmaf(hs[k], w3[(size_t)k * 784 + j], acc);
        out[OUT_REC + b * 784 + j] = 1.f / (1.f + __expf(-acc));
    }
}

// ---------------- launcher ----------------
extern "C" void kernel_launch(void* const* d_in, const int* in_sizes, int n_in,
                              void* d_out, int out_size, void* d_ws, size_t ws_size,
                              hipStream_t stream) {
    const float* imgs = (const float*)d_in[0];
    const float* c1w  = (const float*)d_in[1];
    const float* c1b  = (const float*)d_in[2];
    const float* c2w  = (const float*)d_in[3];
    const float* c2b  = (const float*)d_in[4];
    const float* Wd   = (const float*)d_in[5];
    const float* dw1  = (const float*)d_in[6];
    const float* db1  = (const float*)d_in[7];
    const float* dw2  = (const float*)d_in[8];
    const float* db2  = (const float*)d_in[9];
    const float* dw3  = (const float*)d_in[10];
    const float* db3  = (const float*)d_in[11];

    float* out = (float*)d_out;
    float* ws  = (float*)d_ws;
    ushort* x1h = (ushort*)(ws + WS_X1H);
    ushort* x1l = (ushort*)(ws + WS_X1L);
    ushort* wbh = (ushort*)(ws + WS_BH);
    ushort* wbl = (ushort*)(ws + WS_BL);
    float* p    = ws + WS_P;
    float* u    = ws + WS_U;
    float* v    = ws + WS_V;
    float* h1   = ws + WS_H1;
    float* h2   = ws + WS_H2;
    int*   cls  = (int*)(ws + WS_CLS);
    float* wt32 = ws + WS_X1H;   // reuses x1h region (dead after k_conv2s)

    k_conv1<<<BB * 20, 256, 0, stream>>>(imgs, c1w, c1b, x1h, x1l);
    k_prep_w<<<256, 256, 0, stream>>>(c2w, wbh, wbl);
    k_conv2s<<<BB * 2, 512, 0, stream>>>(x1h, x1l, wbh, wbl, c2b, p);
    k_squash<<<BB * NCAP / 256, 256, 0, stream>>>(p, u);
    k_prep_wt<<<720, 256, 0, stream>>>(Wd, wt32);   // after conv2s: x1h region now free
    k_route5<<<(BB / 2) * NCLS, 256, 0, stream>>>(u, wt32, v);
    k_head<<<BB, 64, 0, stream>>>(v, out, cls);
    k_dec1<<<BB * 512 / 256, 256, 0, stream>>>(v, cls, dw1, db1, h1);
    k_dec2<<<BB * 4, 256, 0, stream>>>(h1, dw2, db2, h2);
    k_dec3<<<BB * 4, 256, 0, stream>>>(h2, dw3, db3, out);
}